// Round 1
// baseline (2173.369 us; speedup 1.0000x reference)
//
#include <hip/hip_runtime.h>

// Problem constants
#define B_TOK 8192
#define D_DIM 1024
#define H_DIM 4096
#define E_NUM 8
#define C_DIM 1024

typedef unsigned short ushort_t;
typedef __attribute__((ext_vector_type(8))) short bf16x8;   // 8 bf16 = 4 VGPRs
typedef __attribute__((ext_vector_type(4))) float f32x4;    // MFMA acc

// round-to-nearest-even fp32 -> bf16
__device__ inline ushort_t f2bf(float f) {
    unsigned u = __float_as_uint(f);
    unsigned r = (u + 0x7fffu + ((u >> 16) & 1u)) >> 16;
    return (ushort_t)r;
}

// async global->LDS, 16B per lane. HW dest = wave-uniform base + lane*16.
__device__ inline void async16(const ushort_t* g, void* l) {
    __builtin_amdgcn_global_load_lds((__attribute__((address_space(1))) void*)g,
                                     (__attribute__((address_space(3))) void*)l,
                                     16, 0, 0);
}

// ---------------------------------------------------------------------------
// GEMM C[M,N] = A[M,K] @ Bt[N,K]^T   (A, Bt bf16 row-major; fp32 accumulate)
// Block: 256 thr (4 waves), tile 128x128, BK=32, wave does 64x64 via 4x4 MFMAs.
// FC1: out = relu(C + bias) stored bf16, row stride ldc
// FC2: out = C + bias stored fp32, row stride ldc
// ---------------------------------------------------------------------------
template <bool FC1>
__global__ __launch_bounds__(256) void gemm_bt(
    const ushort_t* __restrict__ A, const ushort_t* __restrict__ Bt,
    const float* __restrict__ bias, ushort_t* __restrict__ outH,
    float* __restrict__ outF, int M, int N, int K, int ldc)
{
    __shared__ __align__(16) ushort_t As[128 * 32];  // 8 KB
    __shared__ __align__(16) ushort_t Bs[128 * 32];  // 8 KB

    const int tid  = threadIdx.x;
    const int w    = tid >> 6;
    const int lane = tid & 63;
    const int wm   = w >> 1, wn = w & 1;
    const int m0 = blockIdx.y * 128, n0 = blockIdx.x * 128;

    // staging: wave w covers bytes [w*2048, w*2048+2048) of each 8KB tile
    const int o1 = w * 2048 + lane * 16;  // byte offset, chunk 1
    const int o2 = o1 + 1024;             // chunk 2 (row +16)
    const int r1 = o1 >> 6;               // tile row (64B = one 32-elem row)
    const int kk = (o1 & 63) >> 1;        // k element offset within row

    const ushort_t* pa = A  + (size_t)(m0 + r1) * K + kk;
    const ushort_t* pb = Bt + (size_t)(n0 + r1) * K + kk;
    const size_t rowstep = (size_t)16 * K;

    char* ldsA1 = (char*)As + o1; char* ldsA2 = (char*)As + o2;
    char* ldsB1 = (char*)Bs + o1; char* ldsB2 = (char*)Bs + o2;

    f32x4 acc[4][4];
#pragma unroll
    for (int i = 0; i < 4; i++)
#pragma unroll
        for (int j = 0; j < 4; j++) acc[i][j] = (f32x4){0.f, 0.f, 0.f, 0.f};

    const bf16x8* Asv = (const bf16x8*)As;
    const bf16x8* Bsv = (const bf16x8*)Bs;
    // A frag: row = wm*64 + mi*16 + (lane&15), k-chunk = (lane>>4)*8
    const int ar = (wm * 64 + (lane & 15)) * 4 + (lane >> 4);
    const int br = (wn * 64 + (lane & 15)) * 4 + (lane >> 4);

    for (int kt = 0; kt < K; kt += 32) {
        async16(pa, ldsA1);
        async16(pa + rowstep, ldsA2);
        async16(pb, ldsB1);
        async16(pb + rowstep, ldsB2);
        pa += 32; pb += 32;
        __syncthreads();  // drains vmcnt(0) then barrier

        bf16x8 af[4], bg_[4];
#pragma unroll
        for (int i = 0; i < 4; i++) af[i] = Asv[ar + i * 64];
#pragma unroll
        for (int j = 0; j < 4; j++) bg_[j] = Bsv[br + j * 64];
#pragma unroll
        for (int i = 0; i < 4; i++)
#pragma unroll
            for (int j = 0; j < 4; j++)
                acc[i][j] = __builtin_amdgcn_mfma_f32_16x16x32_bf16(
                    af[i], bg_[j], acc[i][j], 0, 0, 0);
        __syncthreads();
    }

    // epilogue: C/D layout col=lane&15, row=(lane>>4)*4+reg  [m89/m91-verified]
    const int colq = lane & 15, rowq = (lane >> 4) * 4;
#pragma unroll
    for (int j = 0; j < 4; j++) {
        int col = n0 + wn * 64 + j * 16 + colq;
        float bv = bias[col];
#pragma unroll
        for (int i = 0; i < 4; i++) {
            int rowb = m0 + wm * 64 + i * 16 + rowq;
#pragma unroll
            for (int r = 0; r < 4; r++) {
                float v = acc[i][j][r] + bv;
                if (FC1) {
                    v = v > 0.f ? v : 0.f;
                    outH[(size_t)(rowb + r) * ldc + col] = f2bf(v);
                } else {
                    outF[(size_t)(rowb + r) * ldc + col] = v;
                }
            }
        }
    }
}

// ---------------------------------------------------------------------------
// 32x32 tiled transpose + fp32->bf16: in [R,C] -> out [C,R]
// ---------------------------------------------------------------------------
__global__ __launch_bounds__(256) void transpose_cvt(
    const float* __restrict__ in, ushort_t* __restrict__ out, int R, int C)
{
    __shared__ float t[32][33];
    int c0 = blockIdx.x * 32, r0 = blockIdx.y * 32;
    int tx = threadIdx.x, ty = threadIdx.y;
#pragma unroll
    for (int i = 0; i < 4; i++)
        t[ty + i * 8][tx] = in[(size_t)(r0 + ty + i * 8) * C + c0 + tx];
    __syncthreads();
#pragma unroll
    for (int i = 0; i < 4; i++)
        out[(size_t)(c0 + ty + i * 8) * R + r0 + tx] = f2bf(t[tx][ty + i * 8]);
}

// fp32 -> bf16 elementwise, 4 elems/thread
__global__ __launch_bounds__(256) void cvt_bf16x4(
    const float* __restrict__ in, ushort_t* __restrict__ out)
{
    int i = blockIdx.x * 256 + threadIdx.x;
    float4 v = ((const float4*)in)[i];
    unsigned lo = (unsigned)f2bf(v.x) | ((unsigned)f2bf(v.y) << 16);
    unsigned hi = (unsigned)f2bf(v.z) | ((unsigned)f2bf(v.w) << 16);
    ((uint2*)out)[i] = make_uint2(lo, hi);
}

// ---------------------------------------------------------------------------
// Gating: one wave per token. 8 dot products over D=1024, butterfly reduce,
// softmax over E=8. All in fp32 (exact vs ref).
// ---------------------------------------------------------------------------
__global__ __launch_bounds__(256) void gating_kernel(
    const float* __restrict__ x, const float* __restrict__ Wg,
    const float* __restrict__ bg, float* __restrict__ gw)
{
    int lane = threadIdx.x & 63;
    int b = blockIdx.x * 4 + (threadIdx.x >> 6);
    const float* xr = x + (size_t)b * D_DIM;
    float acc[8] = {0, 0, 0, 0, 0, 0, 0, 0};
    for (int k = 0; k < D_DIM / 64; k++) {
        int d = k * 64 + lane;
        float xv = xr[d];
        const float4* wr = (const float4*)(Wg + (size_t)d * 8);
        float4 w0 = wr[0], w1 = wr[1];
        acc[0] += xv * w0.x; acc[1] += xv * w0.y;
        acc[2] += xv * w0.z; acc[3] += xv * w0.w;
        acc[4] += xv * w1.x; acc[5] += xv * w1.y;
        acc[6] += xv * w1.z; acc[7] += xv * w1.w;
    }
#pragma unroll
    for (int off = 32; off > 0; off >>= 1)
#pragma unroll
        for (int e = 0; e < 8; e++) acc[e] += __shfl_xor(acc[e], off, 64);

    float mx = -1e30f;
#pragma unroll
    for (int e = 0; e < 8; e++) { acc[e] += bg[e]; mx = fmaxf(mx, acc[e]); }
    float s = 0.f;
#pragma unroll
    for (int e = 0; e < 8; e++) { acc[e] = expf(acc[e] - mx); s += acc[e]; }
    float outv = acc[0];
#pragma unroll
    for (int e = 1; e < 8; e++) outv = (lane == e) ? acc[e] : outv;
    if (lane < 8) gw[(size_t)b * 8 + lane] = outv / s;
}

// ---------------------------------------------------------------------------
// Mixture: one block per token; thread t handles 4 cols (float4).
// ---------------------------------------------------------------------------
__global__ __launch_bounds__(256) void mixture_kernel(
    const float* __restrict__ gw, const float* __restrict__ eo,
    float* __restrict__ mix)
{
    int b = blockIdx.x, t = threadIdx.x;
    float g[8];
#pragma unroll
    for (int e = 0; e < 8; e++) g[e] = gw[(size_t)b * 8 + e];
    const float4* ep = (const float4*)(eo + (size_t)b * (E_NUM * C_DIM));
    float4 a = make_float4(0.f, 0.f, 0.f, 0.f);
#pragma unroll
    for (int e = 0; e < 8; e++) {
        float4 v = ep[e * 256 + t];
        a.x += g[e] * v.x; a.y += g[e] * v.y;
        a.z += g[e] * v.z; a.w += g[e] * v.w;
    }
    ((float4*)(mix + (size_t)b * C_DIM))[t] = a;
}

// ---------------------------------------------------------------------------
extern "C" void kernel_launch(void* const* d_in, const int* in_sizes, int n_in,
                              void* d_out, int out_size, void* d_ws,
                              size_t ws_size, hipStream_t stream)
{
    const float* x  = (const float*)d_in[0];
    const float* W1 = (const float*)d_in[1];
    const float* b1 = (const float*)d_in[2];
    const float* W2 = (const float*)d_in[3];
    const float* b2 = (const float*)d_in[4];
    const float* Wg = (const float*)d_in[5];
    const float* bg = (const float*)d_in[6];

    // outputs, concatenated flat in return order
    float* mix = (float*)d_out;                        // [B, C]
    float* gw  = mix + (size_t)B_TOK * C_DIM;          // [B, E]
    float* eo  = gw + (size_t)B_TOK * E_NUM;           // [B, E, C]

    // workspace (~96 MB): x_bf16 | W1t_e | W2t_e | h_bf16
    ushort_t* xb  = (ushort_t*)d_ws;                    // B*D
    ushort_t* w1t = xb + (size_t)B_TOK * D_DIM;         // H*D (one expert)
    ushort_t* w2t = w1t + (size_t)H_DIM * D_DIM;        // C*H (one expert)
    ushort_t* hb  = w2t + (size_t)C_DIM * H_DIM;        // B*H

    cvt_bf16x4<<<(B_TOK * D_DIM) / 1024, 256, 0, stream>>>(x, xb);
    gating_kernel<<<B_TOK / 4, 256, 0, stream>>>(x, Wg, bg, gw);

    for (int e = 0; e < E_NUM; e++) {
        // W1[e]: [D,H] -> [H,D] bf16
        transpose_cvt<<<dim3(H_DIM / 32, D_DIM / 32), dim3(32, 8), 0, stream>>>(
            W1 + (size_t)e * D_DIM * H_DIM, w1t, D_DIM, H_DIM);
        // h = relu(x @ W1[e] + b1[e])  [B,H] bf16
        gemm_bt<true><<<dim3(H_DIM / 128, B_TOK / 128), 256, 0, stream>>>(
            xb, w1t, b1 + (size_t)e * H_DIM, hb, nullptr,
            B_TOK, H_DIM, D_DIM, H_DIM);
        // W2[e]: [H,C] -> [C,H] bf16
        transpose_cvt<<<dim3(C_DIM / 32, H_DIM / 32), dim3(32, 8), 0, stream>>>(
            W2 + (size_t)e * H_DIM * C_DIM, w2t, H_DIM, C_DIM);
        // eo[:,e,:] = h @ W2[e] + b2[e]  fp32, row stride E*C
        gemm_bt<false><<<dim3(C_DIM / 128, B_TOK / 128), 256, 0, stream>>>(
            hb, w2t, b2 + (size_t)e * C_DIM, nullptr, eo + (size_t)e * C_DIM,
            B_TOK, C_DIM, H_DIM, E_NUM * C_DIM);
    }

    mixture_kernel<<<B_TOK, 256, 0, stream>>>(gw, eo, mix);
}